// Round 10
// baseline (340.302 us; speedup 1.0000x reference)
//
#include <hip/hip_runtime.h>
#include <hip/hip_bf16.h>
#include <math.h>

#define B_ 16
#define N_ 1024
#define T_ 12
#define DM_ 512
#define H_ 3
#define K_ 3
#define C_ 32
#define RSQRT_DK 0.17677669529663687f

typedef __attribute__((ext_vector_type(8))) short bf16x8;
typedef __attribute__((ext_vector_type(4))) float f32x4;

__device__ __forceinline__ ushort f2bf(float f) {   // RNE float->bf16 bits
  uint u = __float_as_uint(f);
  return (ushort)((u + 0x7FFF + ((u >> 16) & 1)) >> 16);
}
__device__ __forceinline__ float bf2f(ushort h) {
  return __uint_as_float(((uint)h) << 16);
}

// ---------------- K1: temporal embedding LayerNorm over N ----------------
__global__ void k1_temporal_ln(const float* __restrict__ x, const float* __restrict__ posT,
                               const float* __restrict__ gT, const float* __restrict__ bT,
                               float* __restrict__ TEmx) {
  int row = blockIdx.x;                 // b*T + t
  int b = row / T_, t = row - b * T_;
  __shared__ float red[256], red2[256];
  float v[4]; float s = 0.f, s2 = 0.f;
  for (int i = 0; i < 4; ++i) {
    int n = threadIdx.x + (i << 8);
    float val = x[(b * N_ + n) * T_ + t] + posT[t * N_ + n];
    v[i] = val; s += val; s2 += val * val;
  }
  red[threadIdx.x] = s; red2[threadIdx.x] = s2;
  __syncthreads();
  for (int off = 128; off > 0; off >>= 1) {
    if (threadIdx.x < off) { red[threadIdx.x] += red[threadIdx.x + off]; red2[threadIdx.x] += red2[threadIdx.x + off]; }
    __syncthreads();
  }
  float mu = red[0] * (1.f / N_);
  float rs = rsqrtf(red2[0] * (1.f / N_) - mu * mu + 1e-5f);
  for (int i = 0; i < 4; ++i) {
    int n = threadIdx.x + (i << 8);
    TEmx[row * N_ + n] = (v[i] - mu) * rs * gT[n] + bT[n];
  }
}

// ---------------- K2 v2: temporal Q/K/V projections, K-split x4 ----------------
__global__ __launch_bounds__(256) void k2_qkv(const float* __restrict__ TEmx,
                       const float* __restrict__ WQ, const float* __restrict__ WK,
                       const float* __restrict__ WV, float* __restrict__ part) {
  int kc = blockIdx.x, row = blockIdx.y;
  __shared__ float e[256];
  int tid = threadIdx.x;
  e[tid] = TEmx[row * N_ + kc * 256 + tid];
  __syncthreads();
  for (int col = tid; col < 288; col += 256) {
    int which = col / 96, j = col - which * 96;
    const float* W = (which == 0) ? WQ : ((which == 1) ? WK : WV);
    const float* Wp = W + (size_t)(kc * 256) * 96 + j;
    float acc = 0.f;
    #pragma unroll 8
    for (int n = 0; n < 256; ++n) acc += e[n] * Wp[n * 96];
    part[(row * 4 + kc) * 288 + col] = acc;
  }
}

// ---------------- K3a v2: temporal attention, one block per (b,h) ----------------
__global__ __launch_bounds__(256) void k3a_attn(const float* __restrict__ part, const float* __restrict__ res_att,
                         float* __restrict__ reAt_out, float* __restrict__ ctx) {
  int bh = blockIdx.x;               // b*3 + h
  int b = bh / 3, h = bh - b * 3;
  __shared__ float q_l[3 * T_ * 32]; // [sec][t][d]: sec0=Q, sec1=K, sec2=V
  __shared__ float s_l[T_ * T_];
  int tid = threadIdx.x;
  for (int i = tid; i < 1152; i += 256) {
    int sec = i / 384, r = i - sec * 384, t = r >> 5, d = r & 31;
    int col = sec * 96 + h * 32 + d;
    const float* pr = &part[(size_t)((b * T_ + t) * 4) * 288 + col];
    q_l[i] = pr[0] + pr[288] + pr[576] + pr[864];
  }
  __syncthreads();
  if (tid < 144) {
    int qi = tid / 12, ki = tid - qi * 12;
    float acc = 0.f;
    #pragma unroll
    for (int d = 0; d < 32; ++d)
      acc += q_l[qi * 32 + d] * q_l[384 + ki * 32 + d];
    float sv = acc * RSQRT_DK + res_att[(size_t)bh * 144 + tid];
    s_l[tid] = sv;
    reAt_out[(size_t)bh * 144 + tid] = sv;
  }
  __syncthreads();
  if (tid < 12) {
    float mx = -1e30f;
    for (int ki = 0; ki < 12; ++ki) mx = fmaxf(mx, s_l[tid * 12 + ki]);
    float sum = 0.f;
    for (int ki = 0; ki < 12; ++ki) { float p = __expf(s_l[tid * 12 + ki] - mx); s_l[tid * 12 + ki] = p; sum += p; }
    float inv = 1.f / sum;
    for (int ki = 0; ki < 12; ++ki) s_l[tid * 12 + ki] *= inv;
  }
  __syncthreads();
  for (int i = tid; i < 384; i += 256) {
    int qi = i >> 5, d = i & 31;
    float acc = 0.f;
    for (int ki = 0; ki < 12; ++ki)
      acc += s_l[qi * 12 + ki] * q_l[768 + ki * 32 + d];
    ctx[(size_t)(b * T_ + qi) * 96 + h * 32 + d] = acc;
  }
}

// ---------------- K3b v2: ctx @ fc_t + TEmx, LayerNorm; 1024 thr, 1 n/thread ----------------
__global__ __launch_bounds__(1024) void k3b_tat(const float* __restrict__ ctx,
                        const float* __restrict__ fc_t,
                        const float* __restrict__ TEmx, float* __restrict__ TAT) {
  int row = blockIdx.x;
  __shared__ float c_l[96];
  __shared__ float red[16], red2[16];
  int tid = threadIdx.x;
  if (tid < 96) c_l[tid] = ctx[row * 96 + tid];
  __syncthreads();
  float acc = TEmx[row * N_ + tid];
  #pragma unroll 12
  for (int j = 0; j < 96; ++j) acc = fmaf(c_l[j], fc_t[j * N_ + tid], acc);
  float s = acc, s2 = acc * acc;
  #pragma unroll
  for (int off = 32; off > 0; off >>= 1) {
    s  += __shfl_xor(s, off);
    s2 += __shfl_xor(s2, off);
  }
  int w = tid >> 6;
  if ((tid & 63) == 0) { red[w] = s; red2[w] = s2; }
  __syncthreads();
  float ts = 0.f, ts2 = 0.f;
  #pragma unroll
  for (int i = 0; i < 16; ++i) { ts += red[i]; ts2 += red2[i]; }
  float mu = ts * (1.f / N_);
  float rs = rsqrtf(ts2 * (1.f / N_) - mu * mu + 1e-5f);
  TAT[row * N_ + tid] = (acc - mu) * rs;
}

// ---------------- K4 v2: one wave per (b,n); shfl-only LN over 512, no LDS/barriers ----------------
__global__ __launch_bounds__(256) void k4_preconv_ln(const float* __restrict__ TAT, const float* __restrict__ pcw,
                              const float* __restrict__ pcb, const float* __restrict__ posS,
                              const float* __restrict__ gS, const float* __restrict__ bS,
                              float* __restrict__ SEmx) {
  int wid = blockIdx.x * 4 + (threadIdx.x >> 6);   // = b*N + n
  int b = wid >> 10, n = wid & 1023;
  int lane = threadIdx.x & 63;
  float tc[12];
  #pragma unroll
  for (int t = 0; t < 12; ++t) tc[t] = TAT[(b * T_ + t) * N_ + n];   // wave-broadcast loads
  float v[8]; float s = 0.f, s2 = 0.f;
  #pragma unroll
  for (int i = 0; i < 8; ++i) {
    int d = lane + (i << 6);
    const float4* pw = (const float4*)&pcw[d * 12];
    float4 w0 = pw[0], w1 = pw[1], w2 = pw[2];
    float acc = pcb[d];
    acc += tc[0] * w0.x + tc[1] * w0.y + tc[2] * w0.z + tc[3] * w0.w;
    acc += tc[4] * w1.x + tc[5] * w1.y + tc[6] * w1.z + tc[7] * w1.w;
    acc += tc[8] * w2.x + tc[9] * w2.y + tc[10] * w2.z + tc[11] * w2.w;
    acc += posS[(size_t)n * DM_ + d];
    v[i] = acc; s += acc; s2 += acc * acc;
  }
  #pragma unroll
  for (int off = 1; off < 64; off <<= 1) {
    s  += __shfl_xor(s, off);
    s2 += __shfl_xor(s2, off);
  }
  float mu = s * (1.f / DM_);
  float rs = rsqrtf(s2 * (1.f / DM_) - mu * mu + 1e-5f);
  #pragma unroll
  for (int i = 0; i < 8; ++i) {
    int d = lane + (i << 6);
    SEmx[(size_t)wid * DM_ + d] = (v[i] - mu) * rs * gS[d] + bS[d];
  }
}

// ---------------- K5pre: [WQs|WKs] -> bf16 wpre[col][512] ----------------
__global__ void k5_pre(const float* __restrict__ WQs, const float* __restrict__ WKs,
                       ushort* __restrict__ wpre) {
  int idx = blockIdx.x * 256 + threadIdx.x;   // over 512*192
  int k = idx / 192, col = idx - k * 192;
  float v = (col < 96) ? WQs[k * 96 + col] : WKs[k * 96 + (col - 96)];
  wpre[col * 512 + k] = f2bf(v);
}

// ---------------- K8pre: GTU weights -> bf16 wg[(dt*64+co)*32+ic], per-conv offsets 0/6144/16384 ----------------
__global__ void k8_pre(const float* __restrict__ w3, const float* __restrict__ w5,
                       const float* __restrict__ w7, ushort* __restrict__ wg) {
  int idx = blockIdx.x * 256 + threadIdx.x;   // over 30720
  if (idx < 6144) {
    int dt = idx / 2048, rem = idx - dt * 2048, co = rem >> 5, ic = rem & 31;
    wg[idx] = f2bf(w3[(co * 32 + ic) * 3 + dt]);
  } else if (idx < 16384) {
    int ds = idx - 6144;
    int dt = ds / 2048, rem = ds - dt * 2048, co = rem >> 5, ic = rem & 31;
    wg[idx] = f2bf(w5[(co * 32 + ic) * 5 + dt]);
  } else if (idx < 30720) {
    int ds = idx - 16384;
    int dt = ds / 2048, rem = ds - dt * 2048, co = rem >> 5, ic = rem & 31;
    wg[idx] = f2bf(w7[(co * 32 + ic) * 7 + dt]);
  }
}

// ---------------- K5 v5: spatial Q/K projections as bf16 MFMA GEMM ----------------
__global__ __launch_bounds__(256) void k5_qks(const float* __restrict__ SEmx,
                                              const ushort* __restrict__ wpre,
                                              __hip_bfloat16* __restrict__ Qs,
                                              __hip_bfloat16* __restrict__ Ks) {
  int b = blockIdx.y, n0 = blockIdx.x * 32;
  __shared__ __align__(16) ushort SE_h[32 * 520];   // [node][k], pad 8 -> 2-way free
  int tid = threadIdx.x;
  for (int idx = tid; idx < 4096; idx += 256) {
    int r = idx >> 7, cq = idx & 127;
    float4 v = *(const float4*)&SEmx[((size_t)((b << 10) + n0 + r)) * DM_ + cq * 4];
    uint lo = (uint)f2bf(v.x) | ((uint)f2bf(v.y) << 16);
    uint hi = (uint)f2bf(v.z) | ((uint)f2bf(v.w) << 16);
    *(uint2*)&SE_h[r * 520 + cq * 4] = make_uint2(lo, hi);
  }
  __syncthreads();

  int w = tid >> 6, lane = tid & 63, quad = lane >> 4, c16 = lane & 15;
  f32x4 acc[3][2];
  #pragma unroll
  for (int mi = 0; mi < 3; ++mi)
    #pragma unroll
    for (int nt = 0; nt < 2; ++nt) acc[mi][nt] = (f32x4){0.f, 0.f, 0.f, 0.f};

  for (int ks = 0; ks < 16; ++ks) {
    bf16x8 Bf0 = *(const bf16x8*)&SE_h[(0 * 16 + c16) * 520 + ks * 32 + quad * 8];
    bf16x8 Bf1 = *(const bf16x8*)&SE_h[(1 * 16 + c16) * 520 + ks * 32 + quad * 8];
    #pragma unroll
    for (int mi = 0; mi < 3; ++mi) {
      int m = (w * 3 + mi) * 16 + c16;
      bf16x8 Af = *(const bf16x8*)&wpre[m * 512 + ks * 32 + quad * 8];
      acc[mi][0] = __builtin_amdgcn_mfma_f32_16x16x32_bf16(Af, Bf0, acc[mi][0], 0, 0, 0);
      acc[mi][1] = __builtin_amdgcn_mfma_f32_16x16x32_bf16(Af, Bf1, acc[mi][1], 0, 0, 0);
    }
  }
  #pragma unroll
  for (int mi = 0; mi < 3; ++mi) {
    int mb = (w * 3 + mi) * 16;
    #pragma unroll
    for (int nt = 0; nt < 2; ++nt) {
      int node = n0 + nt * 16 + c16;
      #pragma unroll
      for (int r = 0; r < 4; ++r) {
        int m = mb + quad * 4 + r;                 // 0..191
        int j = (m < 96) ? m : m - 96;
        int kk = j >> 5, dd = j & 31;
        __hip_bfloat16* o = (m < 96) ? Qs : Ks;
        o[(((b * K_ + kk) * N_) + node) * 32 + dd] = __float2bfloat16(acc[mi][nt][r]);
      }
    }
  }
}

// ---------------- K6pre v3: pack {adj*mask, cheb} as 2xbf16 in uint; 4 elems/thread ----------------
__global__ void k6_pre(const float* __restrict__ adj, const float* __restrict__ mask,
                       const float* __restrict__ cheb, uint* __restrict__ pk) {
  int idx = (blockIdx.x * 256 + threadIdx.x) * 4;   // over 3*1024*1024
  int mn = idx & (N_ * N_ - 1);                     // N_*N_ % 4 == 0: no wrap inside group
  float4 a = *(const float4*)&adj[mn];
  float4 m = *(const float4*)&mask[idx];
  float4 c = *(const float4*)&cheb[idx];
  uint4 o;
  o.x = (uint)f2bf(a.x * m.x) | ((uint)f2bf(c.x) << 16);
  o.y = (uint)f2bf(a.y * m.y) | ((uint)f2bf(c.y) << 16);
  o.z = (uint)f2bf(a.z * m.z) | ((uint)f2bf(c.z) << 16);
  o.w = (uint)f2bf(a.w * m.w) | ((uint)f2bf(c.w) << 16);
  *(uint4*)&pk[idx] = o;
}

// ---------------- K6 v8: max-free softmax; 8 waves x 8 steps (was 4x16) ----------------
// Same work, half the per-wave serial chain, ~32 waves/CU co-resident (was 24),
// 8 waves cover 128 contiguous pk rows per step (better L2 locality on pk stream).
__global__ __launch_bounds__(512) void k6_spatial(
    const __hip_bfloat16* __restrict__ Qs, const __hip_bfloat16* __restrict__ Ks,
    const uint* __restrict__ pk, const float* __restrict__ x,
    float* __restrict__ rhs) {
  const int b  = blockIdx.x;
  const int k  = blockIdx.y;
  const int n0 = blockIdx.z * 32;
  const ushort* Qb = (const ushort*)(Qs + (size_t)((b * K_ + k) * N_) * 32);
  const ushort* Kb = (const ushort*)(Ks + (size_t)((b * K_ + k) * N_) * 32);
  const uint* pkk = pk + (size_t)k * (N_ * N_);
  const float* xb = x + b * N_ * T_;

  __shared__ float well[8][32];
  __shared__ float wacc[8][32][12];

  const int tid  = threadIdx.x;
  const int w    = tid >> 6, lane = tid & 63;
  const int quad = lane >> 4, c16 = lane & 15;

  bf16x8 bfr0 = *(const bf16x8*)(Kb + (size_t)(n0 + c16) * 32 + quad * 8);
  bf16x8 bfr1 = *(const bf16x8*)(Kb + (size_t)(n0 + 16 + c16) * 32 + quad * 8);

  float el0 = 0.f, el1 = 0.f;
  float acc0[12], acc1[12];
  #pragma unroll
  for (int t = 0; t < 12; ++t) { acc0[t] = 0.f; acc1[t] = 0.f; }

  for (int s = 0; s < 8; ++s) {
    const int m0 = (s * 8 + w) * 16;         // this wave's 16-row chunk
    bf16x8 af = *(const bf16x8*)(Qb + (size_t)(m0 + c16) * 32 + quad * 8);
    f32x4 z = {0.f, 0.f, 0.f, 0.f};
    f32x4 sc0 = __builtin_amdgcn_mfma_f32_16x16x32_bf16(af, bfr0, z, 0, 0, 0);
    f32x4 sc1 = __builtin_amdgcn_mfma_f32_16x16x32_bf16(af, bfr1, z, 0, 0, 0);

    const int mrow = m0 + quad * 4;
    float p0[4], p1[4];
    #pragma unroll
    for (int r = 0; r < 4; ++r) {
      uint p2 = pkk[(size_t)(mrow + r) * N_ + n0 + c16];
      uint q2 = pkk[(size_t)(mrow + r) * N_ + n0 + 16 + c16];
      float sv0 = sc0[r] * RSQRT_DK + __uint_as_float(p2 << 16);
      float sv1 = sc1[r] * RSQRT_DK + __uint_as_float(q2 << 16);
      p0[r] = __expf(sv0); el0 += p0[r];
      p0[r] *= __uint_as_float(p2 & 0xFFFF0000u);
      p1[r] = __expf(sv1); el1 += p1[r];
      p1[r] *= __uint_as_float(q2 & 0xFFFF0000u);
    }
    #pragma unroll
    for (int r = 0; r < 4; ++r) {
      const float4* xr = (const float4*)(xb + (size_t)(mrow + r) * 12);
      float4 xA = xr[0], xB = xr[1], xC = xr[2];
      float xv[12] = {xA.x, xA.y, xA.z, xA.w, xB.x, xB.y, xB.z, xB.w,
                      xC.x, xC.y, xC.z, xC.w};
      float px0 = p0[r], px1 = p1[r];
      #pragma unroll
      for (int t = 0; t < 12; ++t) {
        acc0[t] = fmaf(px0, xv[t], acc0[t]);
        acc1[t] = fmaf(px1, xv[t], acc1[t]);
      }
    }
  }

  #pragma unroll
  for (int off = 16; off <= 32; off <<= 1) {
    el0 += __shfl_xor(el0, off);
    el1 += __shfl_xor(el1, off);
    #pragma unroll
    for (int t = 0; t < 12; ++t) {
      acc0[t] += __shfl_xor(acc0[t], off);
      acc1[t] += __shfl_xor(acc1[t], off);
    }
  }
  if (quad == 0) {
    well[w][c16] = el0;
    #pragma unroll
    for (int t = 0; t < 12; ++t) wacc[w][c16][t] = acc0[t];
  } else if (quad == 1) {
    well[w][16 + c16] = el1;
    #pragma unroll
    for (int t = 0; t < 12; ++t) wacc[w][16 + c16][t] = acc1[t];
  }
  __syncthreads();
  if (tid < 384) {
    int n = tid / 12, t = tid - n * 12;
    float den = 0.f, num = 0.f;
    #pragma unroll
    for (int g = 0; g < 8; ++g) { den += well[g][n]; num += wacc[g][n][t]; }
    rhs[((size_t)(b * K_ + k) * N_ + n0 + n) * 12 + t] = num / den;
  }
}

// ---------------- K8 v7b: v3 skeleton; A-fragments from global wg; no inter-conv barriers.
// tc_h swizzle: write sxq = ((quad&1)<<5) ^ ((quad&2)<<1)  [== per-r ((cc&4)<<3)^((cc&8)>>1)],
// read sxr = ((site&15)<<1) ^ ((c&4)<<3) ^ ((c&8)>>1). Same bijection both sides.
template<int KS, int JV, int JB, int WOFF>
__device__ __forceinline__ void conv_mfma_g(const ushort* X_th, const ushort* __restrict__ wg,
                                            ushort* tc_h, const float* bias0,
                                            int mp, int ntg, int quad, int c16) {
  f32x4 accA[3], accB[3];
  #pragma unroll
  for (int i = 0; i < 3; ++i) { accA[i] = (f32x4){0.f,0.f,0.f,0.f}; accB[i] = (f32x4){0.f,0.f,0.f,0.f}; }
  #pragma unroll
  for (int dt = 0; dt < KS; ++dt) {
    bf16x8 A0 = *(const bf16x8*)&wg[WOFF + (dt * 64 + mp * 16 + c16) * 32 + quad * 8];
    bf16x8 A1 = *(const bf16x8*)&wg[WOFF + (dt * 64 + (mp + 2) * 16 + c16) * 32 + quad * 8];
    #pragma unroll
    for (int i = 0; i < 3; ++i) {
      int nt = ntg * 3 + i;
      int j = nt >> 1, sh = nt & 1;
      bf16x8 Bf = *(const bf16x8*)&X_th[(sh * 16 + c16) * 584 + (j + dt) * 32 + quad * 8];
      accA[i] = __builtin_amdgcn_mfma_f32_16x16x32_bf16(A0, Bf, accA[i], 0, 0, 0);
      accB[i] = __builtin_amdgcn_mfma_f32_16x16x32_bf16(A1, Bf, accB[i], 0, 0, 0);
    }
  }
  int sxq = ((quad & 1) << 5) ^ ((quad & 2) << 1);   // r-independent part of the swizzle
  #pragma unroll
  for (int i = 0; i < 3; ++i) {
    int nt = ntg * 3 + i, j = nt >> 1, sh = nt & 1;
    if (j < JV) {
      int s = sh * 16 + c16;
      int sx = ((s & 15) << 1) ^ sxq;
      #pragma unroll
      for (int r = 0; r < 4; ++r) {
        int cc = mp * 16 + quad * 4 + r;
        float a = accA[i][r] + bias0[cc];
        float g = accB[i][r] + bias0[cc + 32];
        float e2a = __expf(2.f * a);
        float th = 1.f - 2.f / (e2a + 1.f);
        float sg = 1.f / (1.f + __expf(-g));
        tc_h[((s * 32 + cc) * 32 + (JB + j)) ^ sx] = f2bf(th * sg);
      }
    }
  }
}

__global__ __launch_bounds__(1024) void k8_fused(
                       const float* __restrict__ rhs, const float* __restrict__ Theta,
                       const float* __restrict__ x, const float* __restrict__ rw,
                       const float* __restrict__ rb,
                       const ushort* __restrict__ wg,
                       const float* __restrict__ b3, const float* __restrict__ b5,
                       const float* __restrict__ b7,
                       const float* __restrict__ fw, const float* __restrict__ fb,
                       const float* __restrict__ gf, const float* __restrict__ bf,
                       float* __restrict__ out) {
  int bn0 = blockIdx.x * 32;
  int b = bn0 >> 10, n0 = bn0 & 1023;

  __shared__ __align__(16) char uR[50176];
  ushort* X_th = (ushort*)uR;                 // [32 s][18 t][32 ic], site stride 584 shorts
  float*  v_l  = (float*)uR;                  // [32][391] overlay (X dead by then)
  __shared__ __align__(16) ushort tc_h[1024 * 32];
  __shared__ float rhs_l[32 * 36];
  __shared__ float Th_l[96];
  __shared__ float xr_l[32 * 12];
  __shared__ float fw_l[288];
  __shared__ float fb_l[12];
  __shared__ float bias_l[3][64];
  __shared__ float rw_l[32], rb_l[32], gf_l[32], bf_l[32];
  __shared__ float stm[384], str[384];

  int tid = threadIdx.x;
  int w = tid >> 6, lane = tid & 63, quad = lane >> 4, c16 = lane & 15;
  int mp = w & 1, ntg = w >> 1;
  int c = (tid >> 3) & 31;
  int site = (tid & 7) | ((tid >> 8) << 3);

  for (int idx = tid; idx < 1152; idx += 1024) {
    int s = idx / 36, r = idx - s * 36, k = r / 12, t = r - k * 12;
    rhs_l[idx] = rhs[((size_t)(b * 3 + k) * N_ + n0 + s) * 12 + t];
  }
  if (tid < 384) xr_l[tid] = x[(size_t)(b * N_ + n0) * 12 + tid];
  if (tid < 96) Th_l[tid] = Theta[tid];
  if (tid < 288) fw_l[tid] = fw[tid];
  if (tid < 12) fb_l[tid] = fb[tid];
  if (tid < 64) { bias_l[0][tid] = b3[tid]; bias_l[1][tid] = b5[tid]; bias_l[2][tid] = b7[tid]; }
  if (tid >= 64 && tid < 96)  rw_l[tid - 64] = rw[tid - 64];
  if (tid >= 96 && tid < 128) rb_l[tid - 96] = rb[tid - 96];
  if (tid >= 128 && tid < 160) gf_l[tid - 128] = gf[tid - 128];
  if (tid >= 160 && tid < 192) bf_l[tid - 160] = bf[tid - 160];
  __syncthreads();

  {
    float th0 = Th_l[c], th1 = Th_l[32 + c], th2 = Th_l[64 + c];
    const float* rs_ = &rhs_l[site * 36];
    ushort* xo = &X_th[site * 584 + c];
    #pragma unroll
    for (int t = 0; t < 12; ++t) {
      float a = rs_[t] * th0 + rs_[12 + t] * th1 + rs_[24 + t] * th2;
      xo[t * 32] = f2bf(fmaxf(a, 0.f));
    }
  }
  for (int idx = tid; idx < 32 * 6 * 32; idx += 1024) {
    int s = idx / 192, r2 = idx - s * 192, tt = r2 >> 5, ic = r2 & 31;
    X_th[s * 584 + (12 + tt) * 32 + ic] = 0;
  }
  __syncthreads();

  // convs back-to-back: weights from global, disjoint tc_h regions -> no barriers between
  conv_mfma_g<3, 10, 0,      0>(X_th, wg, tc_h, &bias_l[0][0], mp, ntg, quad, c16);
  conv_mfma_g<5, 8, 10,   6144>(X_th, wg, tc_h, &bias_l[1][0], mp, ntg, quad, c16);
  conv_mfma_g<7, 6, 18,  16384>(X_th, wg, tc_h, &bias_l[2][0], mp, ntg, quad, c16);
  __syncthreads();

  float tcv[24];
  {
    int rb2 = (site * 32 + c) * 32;
    int sxr = ((site & 15) << 1) ^ ((c & 4) << 3) ^ ((c & 8) >> 1);
    #pragma unroll
    for (int j = 0; j < 24; ++j)
      tcv[j] = __uint_as_float(((uint)tc_h[(rb2 + j) ^ sxr]) << 16);
  }
  float o[12];
  #pragma unroll
  for (int t = 0; t < 12; ++t) o[t] = fb_l[t];
  #pragma unroll
  for (int j = 0; j < 24; ++j) {
    const float4* fp = (const float4*)&fw_l[j * 12];
    float4 f0 = fp[0], f1 = fp[1], f2 = fp[2];
    float fr[12] = {f0.x, f0.y, f0.z, f0.w, f1.x, f1.y, f1.z, f1.w, f2.x, f2.y, f2.z, f2.w};
    #pragma unroll
    for (int t = 0; t < 12; ++t) o[t] = fmaf(tcv[j], fr[t], o[t]);
  }

  float v[12];
  {
    float rwc = rw_l[c], rbc = rb_l[c];
    const float* xs = &xr_l[site * 12];
    float* vo = &v_l[site * 391 + c * 12];
    #pragma unroll
    for (int t = 0; t < 12; ++t) {
      float xres = xs[t] * rwc + rbc;
      v[t] = fmaxf(xres + fmaxf(o[t], 0.f), 0.f);
      vo[t] = v[t];
    }
  }
  __syncthreads();
  if (tid < 384) {
    int s = tid / 12, t = tid - s * 12;
    float sm = 0.f, s2 = 0.f;
    #pragma unroll 8
    for (int cc = 0; cc < 32; ++cc) {
      float u = v_l[s * 391 + cc * 12 + t];
      sm += u; s2 += u * u;
    }
    float m = sm * (1.f / 32.f);
    stm[tid] = m;
    str[tid] = rsqrtf(s2 * (1.f / 32.f) - m * m + 1e-5f);
  }
  __syncthreads();
  {
    float gfc = gf_l[c], bfc = bf_l[c];
    const float* sm_ = &stm[site * 12];
    const float* sr_ = &str[site * 12];
    float q[12];
    #pragma unroll
    for (int t = 0; t < 12; ++t) q[t] = (v[t] - sm_[t]) * sr_[t] * gfc + bfc;
    float* op = &out[(size_t)(bn0 + site) * 384 + c * 12];
    ((float4*)op)[0] = make_float4(q[0], q[1], q[2], q[3]);
    ((float4*)op)[1] = make_float4(q[4], q[5], q[6], q[7]);
    ((float4*)op)[2] = make_float4(q[8], q[9], q[10], q[11]);
  }
}

// ---------------- launch ----------------
extern "C" void kernel_launch(void* const* d_in, const int* in_sizes, int n_in,
                              void* d_out, int out_size, void* d_ws, size_t ws_size,
                              hipStream_t stream) {
  const float* x       = (const float*)d_in[0];
  const float* res_att = (const float*)d_in[1];
  const float* posT    = (const float*)d_in[2];
  const float* gT      = (const float*)d_in[3];
  const float* bT      = (const float*)d_in[4];
  const float* WQt     = (const float*)d_in[5];
  const float* WKt     = (const float*)d_in[6];
  const float* WVt     = (const float*)d_in[7];
  const float* fct     = (const float*)d_in[8];
  const float* pcw     = (const float*)d_in[9];
  const float* pcb     = (const float*)d_in[10];
  const float* posS    = (const float*)d_in[11];
  const float* gS      = (const float*)d_in[12];
  const float* bS      = (const float*)d_in[13];
  const float* WQs     = (const float*)d_in[14];
  const float* WKs     = (const float*)d_in[15];
  const float* cheb    = (const float*)d_in[16];
  const float* adj     = (const float*)d_in[17];
  const float* mask    = (const float*)d_in[18];
  const float* Theta   = (const float*)d_in[19];
  const float* w3      = (const float*)d_in[20];
  const float* b3      = (const float*)d_in[21];
  const float* w5      = (const float*)d_in[22];
  const float* b5      = (const float*)d_in[23];
  const float* w7      = (const float*)d_in[24];
  const float* b7      = (const float*)d_in[25];
  const float* rw      = (const float*)d_in[26];
  const float* rb      = (const float*)d_in[27];
  const float* fw      = (const float*)d_in[28];
  const float* fb      = (const float*)d_in[29];
  const float* gf      = (const float*)d_in[30];
  const float* bf      = (const float*)d_in[31];

  float* ws = (float*)d_ws;
  float* TEmx = ws;                         // 196608
  float* qkv  = TEmx + 196608;              // 55296 (reused: wg = bf16 GTU weights, 15360 fl)
  float* ctx  = qkv + 55296;                // 18432
  float* TAT  = ctx + 18432;                // 196608
  float* SEmx = TAT + 196608;               // 8388608 (reused: part pre-k4, pk during k6)
  float* Qsf  = SEmx + 8388608;             // 1572864 slots (bf16 uses half)
  float* Ksf  = Qsf + 1572864;              // 1572864
  float* rhs  = Ksf + 1572864;              // 589824
  ushort* wpre = (ushort*)(rhs + 589824);   // 98304 shorts
  ushort* wg   = (ushort*)qkv;              // 30720 shorts, inside the unused qkv slot
  float* part = SEmx;                       // overlay: k2 partials, dead before k4

  __hip_bfloat16* Qh = (__hip_bfloat16*)Qsf;
  __hip_bfloat16* Kh = (__hip_bfloat16*)Ksf;
  uint* pk = (uint*)SEmx;                   // 3M uints = 12 MB, dead after k6

  float* out  = (float*)d_out;
  float* reAt = out + 6291456;

  k5_pre<<<(DM_ * 192) / 256, 256, 0, stream>>>(WQs, WKs, wpre);
  k8_pre<<<120, 256, 0, stream>>>(w3, w5, w7, wg);
  k1_temporal_ln<<<B_ * T_, 256, 0, stream>>>(x, posT, gT, bT, TEmx);
  k2_qkv<<<dim3(4, B_ * T_), 256, 0, stream>>>(TEmx, WQt, WKt, WVt, part);
  k3a_attn<<<B_ * H_, 256, 0, stream>>>(part, res_att, reAt, ctx);
  k3b_tat<<<B_ * T_, 1024, 0, stream>>>(ctx, fct, TEmx, TAT);
  k4_preconv_ln<<<B_ * N_ / 4, 256, 0, stream>>>(TAT, pcw, pcb, posS, gS, bS, SEmx);
  k5_qks<<<dim3(N_ / 32, B_), 256, 0, stream>>>(SEmx, wpre, Qh, Kh);
  k6_pre<<<(K_ * N_ * N_) / 1024, 256, 0, stream>>>(adj, mask, cheb, pk);
  k6_spatial<<<dim3(B_, K_, N_ / 32), 512, 0, stream>>>(Qh, Kh, pk, x, rhs);
  k8_fused<<<B_ * N_ / 32, 1024, 0, stream>>>(rhs, Theta, x, rw, rb,
                                              wg, b3, b5, b7, fw, fb, gf, bf, out);
}

// Round 11
// 315.512 us; speedup vs baseline: 1.0786x; 1.0786x over previous
//
#include <hip/hip_runtime.h>
#include <hip/hip_bf16.h>
#include <math.h>

#define B_ 16
#define N_ 1024
#define T_ 12
#define DM_ 512
#define H_ 3
#define K_ 3
#define C_ 32
#define RSQRT_DK 0.17677669529663687f

typedef __attribute__((ext_vector_type(8))) short bf16x8;
typedef __attribute__((ext_vector_type(4))) float f32x4;

__device__ __forceinline__ ushort f2bf(float f) {   // RNE float->bf16 bits
  uint u = __float_as_uint(f);
  return (ushort)((u + 0x7FFF + ((u >> 16) & 1)) >> 16);
}
__device__ __forceinline__ float bf2f(ushort h) {
  return __uint_as_float(((uint)h) << 16);
}

// ---------------- K1: temporal embedding LayerNorm over N ----------------
__global__ void k1_temporal_ln(const float* __restrict__ x, const float* __restrict__ posT,
                               const float* __restrict__ gT, const float* __restrict__ bT,
                               float* __restrict__ TEmx) {
  int row = blockIdx.x;                 // b*T + t
  int b = row / T_, t = row - b * T_;
  __shared__ float red[256], red2[256];
  float v[4]; float s = 0.f, s2 = 0.f;
  for (int i = 0; i < 4; ++i) {
    int n = threadIdx.x + (i << 8);
    float val = x[(b * N_ + n) * T_ + t] + posT[t * N_ + n];
    v[i] = val; s += val; s2 += val * val;
  }
  red[threadIdx.x] = s; red2[threadIdx.x] = s2;
  __syncthreads();
  for (int off = 128; off > 0; off >>= 1) {
    if (threadIdx.x < off) { red[threadIdx.x] += red[threadIdx.x + off]; red2[threadIdx.x] += red2[threadIdx.x + off]; }
    __syncthreads();
  }
  float mu = red[0] * (1.f / N_);
  float rs = rsqrtf(red2[0] * (1.f / N_) - mu * mu + 1e-5f);
  for (int i = 0; i < 4; ++i) {
    int n = threadIdx.x + (i << 8);
    TEmx[row * N_ + n] = (v[i] - mu) * rs * gT[n] + bT[n];
  }
}

// ---------------- K2 v2: temporal Q/K/V projections, K-split x4 ----------------
__global__ __launch_bounds__(256) void k2_qkv(const float* __restrict__ TEmx,
                       const float* __restrict__ WQ, const float* __restrict__ WK,
                       const float* __restrict__ WV, float* __restrict__ part) {
  int kc = blockIdx.x, row = blockIdx.y;
  __shared__ float e[256];
  int tid = threadIdx.x;
  e[tid] = TEmx[row * N_ + kc * 256 + tid];
  __syncthreads();
  for (int col = tid; col < 288; col += 256) {
    int which = col / 96, j = col - which * 96;
    const float* W = (which == 0) ? WQ : ((which == 1) ? WK : WV);
    const float* Wp = W + (size_t)(kc * 256) * 96 + j;
    float acc = 0.f;
    #pragma unroll 8
    for (int n = 0; n < 256; ++n) acc += e[n] * Wp[n * 96];
    part[(row * 4 + kc) * 288 + col] = acc;
  }
}

// ---------------- K3a v2: temporal attention, one block per (b,h) ----------------
__global__ __launch_bounds__(256) void k3a_attn(const float* __restrict__ part, const float* __restrict__ res_att,
                         float* __restrict__ reAt_out, float* __restrict__ ctx) {
  int bh = blockIdx.x;               // b*3 + h
  int b = bh / 3, h = bh - b * 3;
  __shared__ float q_l[3 * T_ * 32]; // [sec][t][d]: sec0=Q, sec1=K, sec2=V
  __shared__ float s_l[T_ * T_];
  int tid = threadIdx.x;
  for (int i = tid; i < 1152; i += 256) {
    int sec = i / 384, r = i - sec * 384, t = r >> 5, d = r & 31;
    int col = sec * 96 + h * 32 + d;
    const float* pr = &part[(size_t)((b * T_ + t) * 4) * 288 + col];
    q_l[i] = pr[0] + pr[288] + pr[576] + pr[864];
  }
  __syncthreads();
  if (tid < 144) {
    int qi = tid / 12, ki = tid - qi * 12;
    float acc = 0.f;
    #pragma unroll
    for (int d = 0; d < 32; ++d)
      acc += q_l[qi * 32 + d] * q_l[384 + ki * 32 + d];
    float sv = acc * RSQRT_DK + res_att[(size_t)bh * 144 + tid];
    s_l[tid] = sv;
    reAt_out[(size_t)bh * 144 + tid] = sv;
  }
  __syncthreads();
  if (tid < 12) {
    float mx = -1e30f;
    for (int ki = 0; ki < 12; ++ki) mx = fmaxf(mx, s_l[tid * 12 + ki]);
    float sum = 0.f;
    for (int ki = 0; ki < 12; ++ki) { float p = __expf(s_l[tid * 12 + ki] - mx); s_l[tid * 12 + ki] = p; sum += p; }
    float inv = 1.f / sum;
    for (int ki = 0; ki < 12; ++ki) s_l[tid * 12 + ki] *= inv;
  }
  __syncthreads();
  for (int i = tid; i < 384; i += 256) {
    int qi = i >> 5, d = i & 31;
    float acc = 0.f;
    for (int ki = 0; ki < 12; ++ki)
      acc += s_l[qi * 12 + ki] * q_l[768 + ki * 32 + d];
    ctx[(size_t)(b * T_ + qi) * 96 + h * 32 + d] = acc;
  }
}

// ---------------- K3b v2: ctx @ fc_t + TEmx, LayerNorm; 1024 thr, 1 n/thread ----------------
__global__ __launch_bounds__(1024) void k3b_tat(const float* __restrict__ ctx,
                        const float* __restrict__ fc_t,
                        const float* __restrict__ TEmx, float* __restrict__ TAT) {
  int row = blockIdx.x;
  __shared__ float c_l[96];
  __shared__ float red[16], red2[16];
  int tid = threadIdx.x;
  if (tid < 96) c_l[tid] = ctx[row * 96 + tid];
  __syncthreads();
  float acc = TEmx[row * N_ + tid];
  #pragma unroll 12
  for (int j = 0; j < 96; ++j) acc = fmaf(c_l[j], fc_t[j * N_ + tid], acc);
  float s = acc, s2 = acc * acc;
  #pragma unroll
  for (int off = 32; off > 0; off >>= 1) {
    s  += __shfl_xor(s, off);
    s2 += __shfl_xor(s2, off);
  }
  int w = tid >> 6;
  if ((tid & 63) == 0) { red[w] = s; red2[w] = s2; }
  __syncthreads();
  float ts = 0.f, ts2 = 0.f;
  #pragma unroll
  for (int i = 0; i < 16; ++i) { ts += red[i]; ts2 += red2[i]; }
  float mu = ts * (1.f / N_);
  float rs = rsqrtf(ts2 * (1.f / N_) - mu * mu + 1e-5f);
  TAT[row * N_ + tid] = (acc - mu) * rs;
}

// ---------------- K4 v2: one wave per (b,n); shfl-only LN over 512, no LDS/barriers ----------------
__global__ __launch_bounds__(256) void k4_preconv_ln(const float* __restrict__ TAT, const float* __restrict__ pcw,
                              const float* __restrict__ pcb, const float* __restrict__ posS,
                              const float* __restrict__ gS, const float* __restrict__ bS,
                              float* __restrict__ SEmx) {
  int wid = blockIdx.x * 4 + (threadIdx.x >> 6);   // = b*N + n
  int b = wid >> 10, n = wid & 1023;
  int lane = threadIdx.x & 63;
  float tc[12];
  #pragma unroll
  for (int t = 0; t < 12; ++t) tc[t] = TAT[(b * T_ + t) * N_ + n];   // wave-broadcast loads
  float v[8]; float s = 0.f, s2 = 0.f;
  #pragma unroll
  for (int i = 0; i < 8; ++i) {
    int d = lane + (i << 6);
    const float4* pw = (const float4*)&pcw[d * 12];
    float4 w0 = pw[0], w1 = pw[1], w2 = pw[2];
    float acc = pcb[d];
    acc += tc[0] * w0.x + tc[1] * w0.y + tc[2] * w0.z + tc[3] * w0.w;
    acc += tc[4] * w1.x + tc[5] * w1.y + tc[6] * w1.z + tc[7] * w1.w;
    acc += tc[8] * w2.x + tc[9] * w2.y + tc[10] * w2.z + tc[11] * w2.w;
    acc += posS[(size_t)n * DM_ + d];
    v[i] = acc; s += acc; s2 += acc * acc;
  }
  #pragma unroll
  for (int off = 1; off < 64; off <<= 1) {
    s  += __shfl_xor(s, off);
    s2 += __shfl_xor(s2, off);
  }
  float mu = s * (1.f / DM_);
  float rs = rsqrtf(s2 * (1.f / DM_) - mu * mu + 1e-5f);
  #pragma unroll
  for (int i = 0; i < 8; ++i) {
    int d = lane + (i << 6);
    SEmx[(size_t)wid * DM_ + d] = (v[i] - mu) * rs * gS[d] + bS[d];
  }
}

// ---------------- K5pre: [WQs|WKs] -> bf16 wpre[col][512] ----------------
__global__ void k5_pre(const float* __restrict__ WQs, const float* __restrict__ WKs,
                       ushort* __restrict__ wpre) {
  int idx = blockIdx.x * 256 + threadIdx.x;   // over 512*192
  int k = idx / 192, col = idx - k * 192;
  float v = (col < 96) ? WQs[k * 96 + col] : WKs[k * 96 + (col - 96)];
  wpre[col * 512 + k] = f2bf(v);
}

// ---------------- K8pre: GTU weights -> bf16 wg[(dt*64+co)*32+ic], per-conv offsets 0/6144/16384 ----------------
__global__ void k8_pre(const float* __restrict__ w3, const float* __restrict__ w5,
                       const float* __restrict__ w7, ushort* __restrict__ wg) {
  int idx = blockIdx.x * 256 + threadIdx.x;   // over 30720
  if (idx < 6144) {
    int dt = idx / 2048, rem = idx - dt * 2048, co = rem >> 5, ic = rem & 31;
    wg[idx] = f2bf(w3[(co * 32 + ic) * 3 + dt]);
  } else if (idx < 16384) {
    int ds = idx - 6144;
    int dt = ds / 2048, rem = ds - dt * 2048, co = rem >> 5, ic = rem & 31;
    wg[idx] = f2bf(w5[(co * 32 + ic) * 5 + dt]);
  } else if (idx < 30720) {
    int ds = idx - 16384;
    int dt = ds / 2048, rem = ds - dt * 2048, co = rem >> 5, ic = rem & 31;
    wg[idx] = f2bf(w7[(co * 32 + ic) * 7 + dt]);
  }
}

// ---------------- K5 v5: spatial Q/K projections as bf16 MFMA GEMM ----------------
__global__ __launch_bounds__(256) void k5_qks(const float* __restrict__ SEmx,
                                              const ushort* __restrict__ wpre,
                                              __hip_bfloat16* __restrict__ Qs,
                                              __hip_bfloat16* __restrict__ Ks) {
  int b = blockIdx.y, n0 = blockIdx.x * 32;
  __shared__ __align__(16) ushort SE_h[32 * 520];   // [node][k], pad 8 -> 2-way free
  int tid = threadIdx.x;
  for (int idx = tid; idx < 4096; idx += 256) {
    int r = idx >> 7, cq = idx & 127;
    float4 v = *(const float4*)&SEmx[((size_t)((b << 10) + n0 + r)) * DM_ + cq * 4];
    uint lo = (uint)f2bf(v.x) | ((uint)f2bf(v.y) << 16);
    uint hi = (uint)f2bf(v.z) | ((uint)f2bf(v.w) << 16);
    *(uint2*)&SE_h[r * 520 + cq * 4] = make_uint2(lo, hi);
  }
  __syncthreads();

  int w = tid >> 6, lane = tid & 63, quad = lane >> 4, c16 = lane & 15;
  f32x4 acc[3][2];
  #pragma unroll
  for (int mi = 0; mi < 3; ++mi)
    #pragma unroll
    for (int nt = 0; nt < 2; ++nt) acc[mi][nt] = (f32x4){0.f, 0.f, 0.f, 0.f};

  for (int ks = 0; ks < 16; ++ks) {
    bf16x8 Bf0 = *(const bf16x8*)&SE_h[(0 * 16 + c16) * 520 + ks * 32 + quad * 8];
    bf16x8 Bf1 = *(const bf16x8*)&SE_h[(1 * 16 + c16) * 520 + ks * 32 + quad * 8];
    #pragma unroll
    for (int mi = 0; mi < 3; ++mi) {
      int m = (w * 3 + mi) * 16 + c16;
      bf16x8 Af = *(const bf16x8*)&wpre[m * 512 + ks * 32 + quad * 8];
      acc[mi][0] = __builtin_amdgcn_mfma_f32_16x16x32_bf16(Af, Bf0, acc[mi][0], 0, 0, 0);
      acc[mi][1] = __builtin_amdgcn_mfma_f32_16x16x32_bf16(Af, Bf1, acc[mi][1], 0, 0, 0);
    }
  }
  #pragma unroll
  for (int mi = 0; mi < 3; ++mi) {
    int mb = (w * 3 + mi) * 16;
    #pragma unroll
    for (int nt = 0; nt < 2; ++nt) {
      int node = n0 + nt * 16 + c16;
      #pragma unroll
      for (int r = 0; r < 4; ++r) {
        int m = mb + quad * 4 + r;                 // 0..191
        int j = (m < 96) ? m : m - 96;
        int kk = j >> 5, dd = j & 31;
        __hip_bfloat16* o = (m < 96) ? Qs : Ks;
        o[(((b * K_ + kk) * N_) + node) * 32 + dd] = __float2bfloat16(acc[mi][nt][r]);
      }
    }
  }
}

// ---------------- K6pre v3: pack {adj*mask, cheb} as 2xbf16 in uint; 4 elems/thread ----------------
__global__ void k6_pre(const float* __restrict__ adj, const float* __restrict__ mask,
                       const float* __restrict__ cheb, uint* __restrict__ pk) {
  int idx = (blockIdx.x * 256 + threadIdx.x) * 4;   // over 3*1024*1024
  int mn = idx & (N_ * N_ - 1);                     // N_*N_ % 4 == 0: no wrap inside group
  float4 a = *(const float4*)&adj[mn];
  float4 m = *(const float4*)&mask[idx];
  float4 c = *(const float4*)&cheb[idx];
  uint4 o;
  o.x = (uint)f2bf(a.x * m.x) | ((uint)f2bf(c.x) << 16);
  o.y = (uint)f2bf(a.y * m.y) | ((uint)f2bf(c.y) << 16);
  o.z = (uint)f2bf(a.z * m.z) | ((uint)f2bf(c.z) << 16);
  o.w = (uint)f2bf(a.w * m.w) | ((uint)f2bf(c.w) << 16);
  *(uint4*)&pk[idx] = o;
}

// ---------------- K6 v9: v7 body (4 waves x 16 steps, max-free) + XCD-share grid swizzle ----------------
// 1D grid d in [0,1536). d = (g%8) + 8*(b + 16*(g/8)), g = k*32 + n0z. All 16 b-blocks of a
// group g get d ≡ g (mod 8) -> same XCD (round-robin dispatch) AND are co-resident
// (6 blk/CU x 32 CU = 192 = one XCD's share) -> the group's 128 KB pk column-slice is
// fetched into that XCD's L2 once instead of 8x. Bijective: q=d>>3; b=q&15; g=((q>>4)<<3)|(d&7).
__global__ __launch_bounds__(256) void k6_spatial(
    const __hip_bfloat16* __restrict__ Qs, const __hip_bfloat16* __restrict__ Ks,
    const uint* __restrict__ pk, const float* __restrict__ x,
    float* __restrict__ rhs) {
  const int d  = blockIdx.x;
  const int q_ = d >> 3;
  const int b  = q_ & 15;
  const int g  = ((q_ >> 4) << 3) | (d & 7);
  const int k  = g >> 5;
  const int n0 = (g & 31) << 5;
  const ushort* Qb = (const ushort*)(Qs + (size_t)((b * K_ + k) * N_) * 32);
  const ushort* Kb = (const ushort*)(Ks + (size_t)((b * K_ + k) * N_) * 32);
  const uint* pkk = pk + (size_t)k * (N_ * N_);
  const float* xb = x + b * N_ * T_;

  __shared__ float well[4][32];
  __shared__ float wacc[4][32][12];

  const int tid  = threadIdx.x;
  const int w    = tid >> 6, lane = tid & 63;
  const int quad = lane >> 4, c16 = lane & 15;

  bf16x8 bfr0 = *(const bf16x8*)(Kb + (size_t)(n0 + c16) * 32 + quad * 8);
  bf16x8 bfr1 = *(const bf16x8*)(Kb + (size_t)(n0 + 16 + c16) * 32 + quad * 8);

  float el0 = 0.f, el1 = 0.f;
  float acc0[12], acc1[12];
  #pragma unroll
  for (int t = 0; t < 12; ++t) { acc0[t] = 0.f; acc1[t] = 0.f; }

  for (int s = 0; s < 16; ++s) {
    const int m0 = s * 64 + w * 16;          // this wave's 16-row chunk
    bf16x8 af = *(const bf16x8*)(Qb + (size_t)(m0 + c16) * 32 + quad * 8);
    f32x4 z = {0.f, 0.f, 0.f, 0.f};
    f32x4 sc0 = __builtin_amdgcn_mfma_f32_16x16x32_bf16(af, bfr0, z, 0, 0, 0);
    f32x4 sc1 = __builtin_amdgcn_mfma_f32_16x16x32_bf16(af, bfr1, z, 0, 0, 0);

    const int mrow = m0 + quad * 4;
    float p0[4], p1[4];
    #pragma unroll
    for (int r = 0; r < 4; ++r) {
      uint p2 = pkk[(size_t)(mrow + r) * N_ + n0 + c16];
      uint q2 = pkk[(size_t)(mrow + r) * N_ + n0 + 16 + c16];
      float sv0 = sc0[r] * RSQRT_DK + __uint_as_float(p2 << 16);
      float sv1 = sc1[r] * RSQRT_DK + __uint_as_float(q2 << 16);
      p0[r] = __expf(sv0); el0 += p0[r];
      p0[r] *= __uint_as_float(p2 & 0xFFFF0000u);
      p1[r] = __expf(sv1); el1 += p1[r];
      p1[r] *= __uint_as_float(q2 & 0xFFFF0000u);
    }
    #pragma unroll
    for (int r = 0; r < 4; ++r) {
      const float4* xr = (const float4*)(xb + (size_t)(mrow + r) * 12);
      float4 xA = xr[0], xB = xr[1], xC = xr[2];
      float xv[12] = {xA.x, xA.y, xA.z, xA.w, xB.x, xB.y, xB.z, xB.w,
                      xC.x, xC.y, xC.z, xC.w};
      float px0 = p0[r], px1 = p1[r];
      #pragma unroll
      for (int t = 0; t < 12; ++t) {
        acc0[t] = fmaf(px0, xv[t], acc0[t]);
        acc1[t] = fmaf(px1, xv[t], acc1[t]);
      }
    }
  }

  #pragma unroll
  for (int off = 16; off <= 32; off <<= 1) {
    el0 += __shfl_xor(el0, off);
    el1 += __shfl_xor(el1, off);
    #pragma unroll
    for (int t = 0; t < 12; ++t) {
      acc0[t] += __shfl_xor(acc0[t], off);
      acc1[t] += __shfl_xor(acc1[t], off);
    }
  }
  if (quad == 0) {
    well[w][c16] = el0;
    #pragma unroll
    for (int t = 0; t < 12; ++t) wacc[w][c16][t] = acc0[t];
  } else if (quad == 1) {
    well[w][16 + c16] = el1;
    #pragma unroll
    for (int t = 0; t < 12; ++t) wacc[w][16 + c16][t] = acc1[t];
  }
  __syncthreads();
  if (tid < 384) {
    int n = tid / 12, t = tid - n * 12;
    float den = well[0][n] + well[1][n] + well[2][n] + well[3][n];
    float num = wacc[0][n][t] + wacc[1][n][t] + wacc[2][n][t] + wacc[3][n][t];
    rhs[((size_t)(b * K_ + k) * N_ + n0 + n) * 12 + t] = num / den;
  }
}

// ---------------- K8 v7b: v3 skeleton; A-fragments from global wg; no inter-conv barriers.
// tc_h swizzle: write sxq = ((quad&1)<<5) ^ ((quad&2)<<1)  [== per-r ((cc&4)<<3)^((cc&8)>>1)],
// read sxr = ((site&15)<<1) ^ ((c&4)<<3) ^ ((c&8)>>1). Same bijection both sides.
template<int KS, int JV, int JB, int WOFF>
__device__ __forceinline__ void conv_mfma_g(const ushort* X_th, const ushort* __restrict__ wg,
                                            ushort* tc_h, const float* bias0,
                                            int mp, int ntg, int quad, int c16) {
  f32x4 accA[3], accB[3];
  #pragma unroll
  for (int i = 0; i < 3; ++i) { accA[i] = (f32x4){0.f,0.f,0.f,0.f}; accB[i] = (f32x4){0.f,0.f,0.f,0.f}; }
  #pragma unroll
  for (int dt = 0; dt < KS; ++dt) {
    bf16x8 A0 = *(const bf16x8*)&wg[WOFF + (dt * 64 + mp * 16 + c16) * 32 + quad * 8];
    bf16x8 A1 = *(const bf16x8*)&wg[WOFF + (dt * 64 + (mp + 2) * 16 + c16) * 32 + quad * 8];
    #pragma unroll
    for (int i = 0; i < 3; ++i) {
      int nt = ntg * 3 + i;
      int j = nt >> 1, sh = nt & 1;
      bf16x8 Bf = *(const bf16x8*)&X_th[(sh * 16 + c16) * 584 + (j + dt) * 32 + quad * 8];
      accA[i] = __builtin_amdgcn_mfma_f32_16x16x32_bf16(A0, Bf, accA[i], 0, 0, 0);
      accB[i] = __builtin_amdgcn_mfma_f32_16x16x32_bf16(A1, Bf, accB[i], 0, 0, 0);
    }
  }
  int sxq = ((quad & 1) << 5) ^ ((quad & 2) << 1);   // r-independent part of the swizzle
  #pragma unroll
  for (int i = 0; i < 3; ++i) {
    int nt = ntg * 3 + i, j = nt >> 1, sh = nt & 1;
    if (j < JV) {
      int s = sh * 16 + c16;
      int sx = ((s & 15) << 1) ^ sxq;
      #pragma unroll
      for (int r = 0; r < 4; ++r) {
        int cc = mp * 16 + quad * 4 + r;
        float a = accA[i][r] + bias0[cc];
        float g = accB[i][r] + bias0[cc + 32];
        float e2a = __expf(2.f * a);
        float th = 1.f - 2.f / (e2a + 1.f);
        float sg = 1.f / (1.f + __expf(-g));
        tc_h[((s * 32 + cc) * 32 + (JB + j)) ^ sx] = f2bf(th * sg);
      }
    }
  }
}

__global__ __launch_bounds__(1024) void k8_fused(
                       const float* __restrict__ rhs, const float* __restrict__ Theta,
                       const float* __restrict__ x, const float* __restrict__ rw,
                       const float* __restrict__ rb,
                       const ushort* __restrict__ wg,
                       const float* __restrict__ b3, const float* __restrict__ b5,
                       const float* __restrict__ b7,
                       const float* __restrict__ fw, const float* __restrict__ fb,
                       const float* __restrict__ gf, const float* __restrict__ bf,
                       float* __restrict__ out) {
  int bn0 = blockIdx.x * 32;
  int b = bn0 >> 10, n0 = bn0 & 1023;

  __shared__ __align__(16) char uR[50176];
  ushort* X_th = (ushort*)uR;                 // [32 s][18 t][32 ic], site stride 584 shorts
  float*  v_l  = (float*)uR;                  // [32][391] overlay (X dead by then)
  __shared__ __align__(16) ushort tc_h[1024 * 32];
  __shared__ float rhs_l[32 * 36];
  __shared__ float Th_l[96];
  __shared__ float xr_l[32 * 12];
  __shared__ float fw_l[288];
  __shared__ float fb_l[12];
  __shared__ float bias_l[3][64];
  __shared__ float rw_l[32], rb_l[32], gf_l[32], bf_l[32];
  __shared__ float stm[384], str[384];

  int tid = threadIdx.x;
  int w = tid >> 6, lane = tid & 63, quad = lane >> 4, c16 = lane & 15;
  int mp = w & 1, ntg = w >> 1;
  int c = (tid >> 3) & 31;
  int site = (tid & 7) | ((tid >> 8) << 3);

  for (int idx = tid; idx < 1152; idx += 1024) {
    int s = idx / 36, r = idx - s * 36, k = r / 12, t = r - k * 12;
    rhs_l[idx] = rhs[((size_t)(b * 3 + k) * N_ + n0 + s) * 12 + t];
  }
  if (tid < 384) xr_l[tid] = x[(size_t)(b * N_ + n0) * 12 + tid];
  if (tid < 96) Th_l[tid] = Theta[tid];
  if (tid < 288) fw_l[tid] = fw[tid];
  if (tid < 12) fb_l[tid] = fb[tid];
  if (tid < 64) { bias_l[0][tid] = b3[tid]; bias_l[1][tid] = b5[tid]; bias_l[2][tid] = b7[tid]; }
  if (tid >= 64 && tid < 96)  rw_l[tid - 64] = rw[tid - 64];
  if (tid >= 96 && tid < 128) rb_l[tid - 96] = rb[tid - 96];
  if (tid >= 128 && tid < 160) gf_l[tid - 128] = gf[tid - 128];
  if (tid >= 160 && tid < 192) bf_l[tid - 160] = bf[tid - 160];
  __syncthreads();

  {
    float th0 = Th_l[c], th1 = Th_l[32 + c], th2 = Th_l[64 + c];
    const float* rs_ = &rhs_l[site * 36];
    ushort* xo = &X_th[site * 584 + c];
    #pragma unroll
    for (int t = 0; t < 12; ++t) {
      float a = rs_[t] * th0 + rs_[12 + t] * th1 + rs_[24 + t] * th2;
      xo[t * 32] = f2bf(fmaxf(a, 0.f));
    }
  }
  for (int idx = tid; idx < 32 * 6 * 32; idx += 1024) {
    int s = idx / 192, r2 = idx - s * 192, tt = r2 >> 5, ic = r2 & 31;
    X_th[s * 584 + (12 + tt) * 32 + ic] = 0;
  }
  __syncthreads();

  // convs back-to-back: weights from global, disjoint tc_h regions -> no barriers between
  conv_mfma_g<3, 10, 0,      0>(X_th, wg, tc_h, &bias_l[0][0], mp, ntg, quad, c16);
  conv_mfma_g<5, 8, 10,   6144>(X_th, wg, tc_h, &bias_l[1][0], mp, ntg, quad, c16);
  conv_mfma_g<7, 6, 18,  16384>(X_th, wg, tc_h, &bias_l[2][0], mp, ntg, quad, c16);
  __syncthreads();

  float tcv[24];
  {
    int rb2 = (site * 32 + c) * 32;
    int sxr = ((site & 15) << 1) ^ ((c & 4) << 3) ^ ((c & 8) >> 1);
    #pragma unroll
    for (int j = 0; j < 24; ++j)
      tcv[j] = __uint_as_float(((uint)tc_h[(rb2 + j) ^ sxr]) << 16);
  }
  float o[12];
  #pragma unroll
  for (int t = 0; t < 12; ++t) o[t] = fb_l[t];
  #pragma unroll
  for (int j = 0; j < 24; ++j) {
    const float4* fp = (const float4*)&fw_l[j * 12];
    float4 f0 = fp[0], f1 = fp[1], f2 = fp[2];
    float fr[12] = {f0.x, f0.y, f0.z, f0.w, f1.x, f1.y, f1.z, f1.w, f2.x, f2.y, f2.z, f2.w};
    #pragma unroll
    for (int t = 0; t < 12; ++t) o[t] = fmaf(tcv[j], fr[t], o[t]);
  }

  float v[12];
  {
    float rwc = rw_l[c], rbc = rb_l[c];
    const float* xs = &xr_l[site * 12];
    float* vo = &v_l[site * 391 + c * 12];
    #pragma unroll
    for (int t = 0; t < 12; ++t) {
      float xres = xs[t] * rwc + rbc;
      v[t] = fmaxf(xres + fmaxf(o[t], 0.f), 0.f);
      vo[t] = v[t];
    }
  }
  __syncthreads();
  if (tid < 384) {
    int s = tid / 12, t = tid - s * 12;
    float sm = 0.f, s2 = 0.f;
    #pragma unroll 8
    for (int cc = 0; cc < 32; ++cc) {
      float u = v_l[s * 391 + cc * 12 + t];
      sm += u; s2 += u * u;
    }
    float m = sm * (1.f / 32.f);
    stm[tid] = m;
    str[tid] = rsqrtf(s2 * (1.f / 32.f) - m * m + 1e-5f);
  }
  __syncthreads();
  {
    float gfc = gf_l[c], bfc = bf_l[c];
    const float* sm_ = &stm[site * 12];
    const float* sr_ = &str[site * 12];
    float q[12];
    #pragma unroll
    for (int t = 0; t < 12; ++t) q[t] = (v[t] - sm_[t]) * sr_[t] * gfc + bfc;
    float* op = &out[(size_t)(bn0 + site) * 384 + c * 12];
    ((float4*)op)[0] = make_float4(q[0], q[1], q[2], q[3]);
    ((float4*)op)[1] = make_float4(q[4], q[5], q[6], q[7]);
    ((float4*)op)[2] = make_float4(q[8], q[9], q[10], q[11]);
  }
}

// ---------------- launch ----------------
extern "C" void kernel_launch(void* const* d_in, const int* in_sizes, int n_in,
                              void* d_out, int out_size, void* d_ws, size_t ws_size,
                              hipStream_t stream) {
  const float* x       = (const float*)d_in[0];
  const float* res_att = (const float*)d_in[1];
  const float* posT    = (const float*)d_in[2];
  const float* gT      = (const float*)d_in[3];
  const float* bT      = (const float*)d_in[4];
  const float* WQt     = (const float*)d_in[5];
  const float* WKt     = (const float*)d_in[6];
  const float* WVt     = (const float*)d_in[7];
  const float* fct     = (const float*)d_in[8];
  const float* pcw     = (const float*)d_in[9];
  const float* pcb     = (const float*)d_in[10];
  const float* posS    = (const float*)d_in[11];
  const float* gS      = (const float*)d_in[12];
  const float* bS      = (const float*)d_in[13];
  const float* WQs     = (const float*)d_in[14];
  const float* WKs     = (const float*)d_in[15];
  const float* cheb    = (const float*)d_in[16];
  const float* adj     = (const float*)d_in[17];
  const float* mask    = (const float*)d_in[18];
  const float* Theta   = (const float*)d_in[19];
  const float* w3      = (const float*)d_in[20];
  const float* b3      = (const float*)d_in[21];
  const float* w5      = (const float*)d_in[22];
  const float* b5      = (const float*)d_in[23];
  const float* w7      = (const float*)d_in[24];
  const float* b7      = (const float*)d_in[25];
  const float* rw      = (const float*)d_in[26];
  const float* rb      = (const float*)d_in[27];
  const float* fw      = (const float*)d_in[28];
  const float* fb      = (const float*)d_in[29];
  const float* gf      = (const float*)d_in[30];
  const float* bf      = (const float*)d_in[31];

  float* ws = (float*)d_ws;
  float* TEmx = ws;                         // 196608
  float* qkv  = TEmx + 196608;              // 55296 (reused: wg = bf16 GTU weights, 15360 fl)
  float* ctx  = qkv + 55296;                // 18432
  float* TAT  = ctx + 18432;                // 196608
  float* SEmx = TAT + 196608;               // 8388608 (reused: part pre-k4, pk during k6)
  float* Qsf  = SEmx + 8388608;             // 1572864 slots (bf16 uses half)
  float* Ksf  = Qsf + 1572864;              // 1572864
  float* rhs  = Ksf + 1572864;              // 589824
  ushort* wpre = (ushort*)(rhs + 589824);   // 98304 shorts
  ushort* wg   = (ushort*)qkv;              // 30720 shorts, inside the unused qkv slot
  float* part = SEmx;                       // overlay: k2 partials, dead before k4

  __hip_bfloat16* Qh = (__hip_bfloat16*)Qsf;
  __hip_bfloat16* Kh = (__hip_bfloat16*)Ksf;
  uint* pk = (uint*)SEmx;                   // 3M uints = 12 MB, dead after k6

  float* out  = (float*)d_out;
  float* reAt = out + 6291456;

  k5_pre<<<(DM_ * 192) / 256, 256, 0, stream>>>(WQs, WKs, wpre);
  k8_pre<<<120, 256, 0, stream>>>(w3, w5, w7, wg);
  k1_temporal_ln<<<B_ * T_, 256, 0, stream>>>(x, posT, gT, bT, TEmx);
  k2_qkv<<<dim3(4, B_ * T_), 256, 0, stream>>>(TEmx, WQt, WKt, WVt, part);
  k3a_attn<<<B_ * H_, 256, 0, stream>>>(part, res_att, reAt, ctx);
  k3b_tat<<<B_ * T_, 1024, 0, stream>>>(ctx, fct, TEmx, TAT);
  k4_preconv_ln<<<B_ * N_ / 4, 256, 0, stream>>>(TAT, pcw, pcb, posS, gS, bS, SEmx);
  k5_qks<<<dim3(N_ / 32, B_), 256, 0, stream>>>(SEmx, wpre, Qh, Kh);
  k6_pre<<<(K_ * N_ * N_) / 1024, 256, 0, stream>>>(adj, mask, cheb, pk);
  k6_spatial<<<B_ * K_ * (N_ / 32), 256, 0, stream>>>(Qh, Kh, pk, x, rhs);
  k8_fused<<<B_ * N_ / 32, 1024, 0, stream>>>(rhs, Theta, x, rw, rb,
                                              wg, b3, b5, b7, fw, fb, gf, bf, out);
}

// Round 12
// 302.396 us; speedup vs baseline: 1.1254x; 1.0434x over previous
//
#include <hip/hip_runtime.h>
#include <hip/hip_bf16.h>
#include <math.h>

#define B_ 16
#define N_ 1024
#define T_ 12
#define DM_ 512
#define H_ 3
#define K_ 3
#define C_ 32
#define RSQRT_DK 0.17677669529663687f

typedef __attribute__((ext_vector_type(8))) short bf16x8;
typedef __attribute__((ext_vector_type(4))) float f32x4;

__device__ __forceinline__ ushort f2bf(float f) {   // RNE float->bf16 bits
  uint u = __float_as_uint(f);
  return (ushort)((u + 0x7FFF + ((u >> 16) & 1)) >> 16);
}
__device__ __forceinline__ float bf2f(ushort h) {
  return __uint_as_float(((uint)h) << 16);
}

// ---------------- K1: temporal embedding LayerNorm over N ----------------
__global__ void k1_temporal_ln(const float* __restrict__ x, const float* __restrict__ posT,
                               const float* __restrict__ gT, const float* __restrict__ bT,
                               float* __restrict__ TEmx) {
  int row = blockIdx.x;                 // b*T + t
  int b = row / T_, t = row - b * T_;
  __shared__ float red[256], red2[256];
  float v[4]; float s = 0.f, s2 = 0.f;
  for (int i = 0; i < 4; ++i) {
    int n = threadIdx.x + (i << 8);
    float val = x[(b * N_ + n) * T_ + t] + posT[t * N_ + n];
    v[i] = val; s += val; s2 += val * val;
  }
  red[threadIdx.x] = s; red2[threadIdx.x] = s2;
  __syncthreads();
  for (int off = 128; off > 0; off >>= 1) {
    if (threadIdx.x < off) { red[threadIdx.x] += red[threadIdx.x + off]; red2[threadIdx.x] += red2[threadIdx.x + off]; }
    __syncthreads();
  }
  float mu = red[0] * (1.f / N_);
  float rs = rsqrtf(red2[0] * (1.f / N_) - mu * mu + 1e-5f);
  for (int i = 0; i < 4; ++i) {
    int n = threadIdx.x + (i << 8);
    TEmx[row * N_ + n] = (v[i] - mu) * rs * gT[n] + bT[n];
  }
}

// ---------------- K2 v2: temporal Q/K/V projections, K-split x4 ----------------
__global__ __launch_bounds__(256) void k2_qkv(const float* __restrict__ TEmx,
                       const float* __restrict__ WQ, const float* __restrict__ WK,
                       const float* __restrict__ WV, float* __restrict__ part) {
  int kc = blockIdx.x, row = blockIdx.y;
  __shared__ float e[256];
  int tid = threadIdx.x;
  e[tid] = TEmx[row * N_ + kc * 256 + tid];
  __syncthreads();
  for (int col = tid; col < 288; col += 256) {
    int which = col / 96, j = col - which * 96;
    const float* W = (which == 0) ? WQ : ((which == 1) ? WK : WV);
    const float* Wp = W + (size_t)(kc * 256) * 96 + j;
    float acc = 0.f;
    #pragma unroll 8
    for (int n = 0; n < 256; ++n) acc += e[n] * Wp[n * 96];
    part[(row * 4 + kc) * 288 + col] = acc;
  }
}

// ---------------- K3a v2: temporal attention, one block per (b,h) ----------------
__global__ __launch_bounds__(256) void k3a_attn(const float* __restrict__ part, const float* __restrict__ res_att,
                         float* __restrict__ reAt_out, float* __restrict__ ctx) {
  int bh = blockIdx.x;               // b*3 + h
  int b = bh / 3, h = bh - b * 3;
  __shared__ float q_l[3 * T_ * 32]; // [sec][t][d]: sec0=Q, sec1=K, sec2=V
  __shared__ float s_l[T_ * T_];
  int tid = threadIdx.x;
  for (int i = tid; i < 1152; i += 256) {
    int sec = i / 384, r = i - sec * 384, t = r >> 5, d = r & 31;
    int col = sec * 96 + h * 32 + d;
    const float* pr = &part[(size_t)((b * T_ + t) * 4) * 288 + col];
    q_l[i] = pr[0] + pr[288] + pr[576] + pr[864];
  }
  __syncthreads();
  if (tid < 144) {
    int qi = tid / 12, ki = tid - qi * 12;
    float acc = 0.f;
    #pragma unroll
    for (int d = 0; d < 32; ++d)
      acc += q_l[qi * 32 + d] * q_l[384 + ki * 32 + d];
    float sv = acc * RSQRT_DK + res_att[(size_t)bh * 144 + tid];
    s_l[tid] = sv;
    reAt_out[(size_t)bh * 144 + tid] = sv;
  }
  __syncthreads();
  if (tid < 12) {
    float mx = -1e30f;
    for (int ki = 0; ki < 12; ++ki) mx = fmaxf(mx, s_l[tid * 12 + ki]);
    float sum = 0.f;
    for (int ki = 0; ki < 12; ++ki) { float p = __expf(s_l[tid * 12 + ki] - mx); s_l[tid * 12 + ki] = p; sum += p; }
    float inv = 1.f / sum;
    for (int ki = 0; ki < 12; ++ki) s_l[tid * 12 + ki] *= inv;
  }
  __syncthreads();
  for (int i = tid; i < 384; i += 256) {
    int qi = i >> 5, d = i & 31;
    float acc = 0.f;
    for (int ki = 0; ki < 12; ++ki)
      acc += s_l[qi * 12 + ki] * q_l[768 + ki * 32 + d];
    ctx[(size_t)(b * T_ + qi) * 96 + h * 32 + d] = acc;
  }
}

// ---------------- K3b v2: ctx @ fc_t + TEmx, LayerNorm; 1024 thr, 1 n/thread ----------------
__global__ __launch_bounds__(1024) void k3b_tat(const float* __restrict__ ctx,
                        const float* __restrict__ fc_t,
                        const float* __restrict__ TEmx, float* __restrict__ TAT) {
  int row = blockIdx.x;
  __shared__ float c_l[96];
  __shared__ float red[16], red2[16];
  int tid = threadIdx.x;
  if (tid < 96) c_l[tid] = ctx[row * 96 + tid];
  __syncthreads();
  float acc = TEmx[row * N_ + tid];
  #pragma unroll 12
  for (int j = 0; j < 96; ++j) acc = fmaf(c_l[j], fc_t[j * N_ + tid], acc);
  float s = acc, s2 = acc * acc;
  #pragma unroll
  for (int off = 32; off > 0; off >>= 1) {
    s  += __shfl_xor(s, off);
    s2 += __shfl_xor(s2, off);
  }
  int w = tid >> 6;
  if ((tid & 63) == 0) { red[w] = s; red2[w] = s2; }
  __syncthreads();
  float ts = 0.f, ts2 = 0.f;
  #pragma unroll
  for (int i = 0; i < 16; ++i) { ts += red[i]; ts2 += red2[i]; }
  float mu = ts * (1.f / N_);
  float rs = rsqrtf(ts2 * (1.f / N_) - mu * mu + 1e-5f);
  TAT[row * N_ + tid] = (acc - mu) * rs;
}

// ---------------- K_prepack: merged k6_pre | k5_pre | k8_pre (independent elementwise) ----------------
__global__ __launch_bounds__(256) void k_prepack(
    const float* __restrict__ adj, const float* __restrict__ mask,
    const float* __restrict__ cheb, uint* __restrict__ pk,
    const float* __restrict__ WQs, const float* __restrict__ WKs,
    ushort* __restrict__ wpre,
    const float* __restrict__ w3, const float* __restrict__ w5,
    const float* __restrict__ w7, ushort* __restrict__ wg) {
  int bid = blockIdx.x, tid = threadIdx.x;
  if (bid < 3072) {              // k6_pre: pack {adj*mask, cheb} as 2xbf16; 4 elems/thread
    int idx = (bid * 256 + tid) * 4;
    int mn = idx & (N_ * N_ - 1);
    float4 a = *(const float4*)&adj[mn];
    float4 m = *(const float4*)&mask[idx];
    float4 c = *(const float4*)&cheb[idx];
    uint4 o;
    o.x = (uint)f2bf(a.x * m.x) | ((uint)f2bf(c.x) << 16);
    o.y = (uint)f2bf(a.y * m.y) | ((uint)f2bf(c.y) << 16);
    o.z = (uint)f2bf(a.z * m.z) | ((uint)f2bf(c.z) << 16);
    o.w = (uint)f2bf(a.w * m.w) | ((uint)f2bf(c.w) << 16);
    *(uint4*)&pk[idx] = o;
  } else if (bid < 3456) {       // k5_pre: [WQs|WKs] -> bf16 wpre[col][512]
    int idx = (bid - 3072) * 256 + tid;
    int k = idx / 192, col = idx - k * 192;
    float v = (col < 96) ? WQs[k * 96 + col] : WKs[k * 96 + (col - 96)];
    wpre[col * 512 + k] = f2bf(v);
  } else {                       // k8_pre: GTU weights -> bf16 wg
    int idx = (bid - 3456) * 256 + tid;
    if (idx < 6144) {
      int dt = idx / 2048, rem = idx - dt * 2048, co = rem >> 5, ic = rem & 31;
      wg[idx] = f2bf(w3[(co * 32 + ic) * 3 + dt]);
    } else if (idx < 16384) {
      int ds = idx - 6144;
      int dt = ds / 2048, rem = ds - dt * 2048, co = rem >> 5, ic = rem & 31;
      wg[idx] = f2bf(w5[(co * 32 + ic) * 5 + dt]);
    } else if (idx < 30720) {
      int ds = idx - 16384;
      int dt = ds / 2048, rem = ds - dt * 2048, co = rem >> 5, ic = rem & 31;
      wg[idx] = f2bf(w7[(co * 32 + ic) * 7 + dt]);
    }
  }
}

// ---------------- K5 v6: k4's preconv+LN fused in front of the bf16 MFMA GEMM ----------------
// Staging: wave w computes nodes r = w*8..w*8+7 with k4's exact shfl-LN (8 dims/lane),
// writing bf16 directly into SE_h — the 33.5 MB SEmx intermediate is eliminated.
__global__ __launch_bounds__(256) void k5_qks(const float* __restrict__ TAT,
                                              const float* __restrict__ pcw,
                                              const float* __restrict__ pcb,
                                              const float* __restrict__ posS,
                                              const float* __restrict__ gS,
                                              const float* __restrict__ bS,
                                              const ushort* __restrict__ wpre,
                                              __hip_bfloat16* __restrict__ Qs,
                                              __hip_bfloat16* __restrict__ Ks) {
  int b = blockIdx.y, n0 = blockIdx.x * 32;
  __shared__ __align__(16) ushort SE_h[32 * 520];   // [node][k], pad 8 -> 2-way free
  int tid = threadIdx.x;
  int w = tid >> 6, lane = tid & 63, quad = (lane >> 4), c16 = lane & 15;

  for (int j = 0; j < 8; ++j) {
    int r = w * 8 + j;
    int n = n0 + r;
    float tc[12];
    #pragma unroll
    for (int t = 0; t < 12; ++t) tc[t] = TAT[(size_t)(b * T_ + t) * N_ + n];  // broadcast
    float vv[8]; float s = 0.f, s2 = 0.f;
    #pragma unroll
    for (int i = 0; i < 8; ++i) {
      int dd = lane + (i << 6);
      const float4* pw = (const float4*)&pcw[dd * 12];
      float4 w0 = pw[0], w1 = pw[1], w2 = pw[2];
      float acc = pcb[dd];
      acc += tc[0] * w0.x + tc[1] * w0.y + tc[2] * w0.z + tc[3] * w0.w;
      acc += tc[4] * w1.x + tc[5] * w1.y + tc[6] * w1.z + tc[7] * w1.w;
      acc += tc[8] * w2.x + tc[9] * w2.y + tc[10] * w2.z + tc[11] * w2.w;
      acc += posS[(size_t)n * DM_ + dd];
      vv[i] = acc; s += acc; s2 += acc * acc;
    }
    #pragma unroll
    for (int off = 1; off < 64; off <<= 1) {
      s  += __shfl_xor(s, off);
      s2 += __shfl_xor(s2, off);
    }
    float mu = s * (1.f / DM_);
    float rs = rsqrtf(s2 * (1.f / DM_) - mu * mu + 1e-5f);
    #pragma unroll
    for (int i = 0; i < 8; ++i) {
      int dd = lane + (i << 6);
      SE_h[r * 520 + dd] = f2bf((vv[i] - mu) * rs * gS[dd] + bS[dd]);
    }
  }
  __syncthreads();

  f32x4 acc[3][2];
  #pragma unroll
  for (int mi = 0; mi < 3; ++mi)
    #pragma unroll
    for (int nt = 0; nt < 2; ++nt) acc[mi][nt] = (f32x4){0.f, 0.f, 0.f, 0.f};

  for (int ks = 0; ks < 16; ++ks) {
    bf16x8 Bf0 = *(const bf16x8*)&SE_h[(0 * 16 + c16) * 520 + ks * 32 + quad * 8];
    bf16x8 Bf1 = *(const bf16x8*)&SE_h[(1 * 16 + c16) * 520 + ks * 32 + quad * 8];
    #pragma unroll
    for (int mi = 0; mi < 3; ++mi) {
      int m = (w * 3 + mi) * 16 + c16;
      bf16x8 Af = *(const bf16x8*)&wpre[m * 512 + ks * 32 + quad * 8];
      acc[mi][0] = __builtin_amdgcn_mfma_f32_16x16x32_bf16(Af, Bf0, acc[mi][0], 0, 0, 0);
      acc[mi][1] = __builtin_amdgcn_mfma_f32_16x16x32_bf16(Af, Bf1, acc[mi][1], 0, 0, 0);
    }
  }
  #pragma unroll
  for (int mi = 0; mi < 3; ++mi) {
    int mb = (w * 3 + mi) * 16;
    #pragma unroll
    for (int nt = 0; nt < 2; ++nt) {
      int node = n0 + nt * 16 + c16;
      #pragma unroll
      for (int r = 0; r < 4; ++r) {
        int m = mb + quad * 4 + r;                 // 0..191
        int j = (m < 96) ? m : m - 96;
        int kk = j >> 5, dd = j & 31;
        __hip_bfloat16* o = (m < 96) ? Qs : Ks;
        o[(((b * K_ + kk) * N_) + node) * 32 + dd] = __float2bfloat16(acc[mi][nt][r]);
      }
    }
  }
}

// ---------------- K6 v9: max-free softmax (4 waves x 16 steps) + XCD-share grid swizzle ----------------
// 1D grid d in [0,1536). d = (g%8) + 8*(b + 16*(g/8)), g = k*32 + n0z. All 16 b-blocks of a
// group g land on one XCD and are co-resident -> group's 128 KB pk slice fetched once/XCD.
__global__ __launch_bounds__(256) void k6_spatial(
    const __hip_bfloat16* __restrict__ Qs, const __hip_bfloat16* __restrict__ Ks,
    const uint* __restrict__ pk, const float* __restrict__ x,
    float* __restrict__ rhs) {
  const int d  = blockIdx.x;
  const int q_ = d >> 3;
  const int b  = q_ & 15;
  const int g  = ((q_ >> 4) << 3) | (d & 7);
  const int k  = g >> 5;
  const int n0 = (g & 31) << 5;
  const ushort* Qb = (const ushort*)(Qs + (size_t)((b * K_ + k) * N_) * 32);
  const ushort* Kb = (const ushort*)(Ks + (size_t)((b * K_ + k) * N_) * 32);
  const uint* pkk = pk + (size_t)k * (N_ * N_);
  const float* xb = x + b * N_ * T_;

  __shared__ float well[4][32];
  __shared__ float wacc[4][32][12];

  const int tid  = threadIdx.x;
  const int w    = tid >> 6, lane = tid & 63;
  const int quad = lane >> 4, c16 = lane & 15;

  bf16x8 bfr0 = *(const bf16x8*)(Kb + (size_t)(n0 + c16) * 32 + quad * 8);
  bf16x8 bfr1 = *(const bf16x8*)(Kb + (size_t)(n0 + 16 + c16) * 32 + quad * 8);

  float el0 = 0.f, el1 = 0.f;
  float acc0[12], acc1[12];
  #pragma unroll
  for (int t = 0; t < 12; ++t) { acc0[t] = 0.f; acc1[t] = 0.f; }

  for (int s = 0; s < 16; ++s) {
    const int m0 = s * 64 + w * 16;          // this wave's 16-row chunk
    bf16x8 af = *(const bf16x8*)(Qb + (size_t)(m0 + c16) * 32 + quad * 8);
    f32x4 z = {0.f, 0.f, 0.f, 0.f};
    f32x4 sc0 = __builtin_amdgcn_mfma_f32_16x16x32_bf16(af, bfr0, z, 0, 0, 0);
    f32x4 sc1 = __builtin_amdgcn_mfma_f32_16x16x32_bf16(af, bfr1, z, 0, 0, 0);

    const int mrow = m0 + quad * 4;
    float p0[4], p1[4];
    #pragma unroll
    for (int r = 0; r < 4; ++r) {
      uint p2 = pkk[(size_t)(mrow + r) * N_ + n0 + c16];
      uint q2 = pkk[(size_t)(mrow + r) * N_ + n0 + 16 + c16];
      float sv0 = sc0[r] * RSQRT_DK + __uint_as_float(p2 << 16);
      float sv1 = sc1[r] * RSQRT_DK + __uint_as_float(q2 << 16);
      p0[r] = __expf(sv0); el0 += p0[r];
      p0[r] *= __uint_as_float(p2 & 0xFFFF0000u);
      p1[r] = __expf(sv1); el1 += p1[r];
      p1[r] *= __uint_as_float(q2 & 0xFFFF0000u);
    }
    #pragma unroll
    for (int r = 0; r < 4; ++r) {
      const float4* xr = (const float4*)(xb + (size_t)(mrow + r) * 12);
      float4 xA = xr[0], xB = xr[1], xC = xr[2];
      float xv[12] = {xA.x, xA.y, xA.z, xA.w, xB.x, xB.y, xB.z, xB.w,
                      xC.x, xC.y, xC.z, xC.w};
      float px0 = p0[r], px1 = p1[r];
      #pragma unroll
      for (int t = 0; t < 12; ++t) {
        acc0[t] = fmaf(px0, xv[t], acc0[t]);
        acc1[t] = fmaf(px1, xv[t], acc1[t]);
      }
    }
  }

  #pragma unroll
  for (int off = 16; off <= 32; off <<= 1) {
    el0 += __shfl_xor(el0, off);
    el1 += __shfl_xor(el1, off);
    #pragma unroll
    for (int t = 0; t < 12; ++t) {
      acc0[t] += __shfl_xor(acc0[t], off);
      acc1[t] += __shfl_xor(acc1[t], off);
    }
  }
  if (quad == 0) {
    well[w][c16] = el0;
    #pragma unroll
    for (int t = 0; t < 12; ++t) wacc[w][c16][t] = acc0[t];
  } else if (quad == 1) {
    well[w][16 + c16] = el1;
    #pragma unroll
    for (int t = 0; t < 12; ++t) wacc[w][16 + c16][t] = acc1[t];
  }
  __syncthreads();
  if (tid < 384) {
    int n = tid / 12, t = tid - n * 12;
    float den = well[0][n] + well[1][n] + well[2][n] + well[3][n];
    float num = wacc[0][n][t] + wacc[1][n][t] + wacc[2][n][t] + wacc[3][n][t];
    rhs[((size_t)(b * K_ + k) * N_ + n0 + n) * 12 + t] = num / den;
  }
}

// ---------------- K8 v7b: v3 skeleton; A-fragments from global wg; no inter-conv barriers.
// tc_h swizzle: write sxq = ((quad&1)<<5) ^ ((quad&2)<<1), read sxr matches per-r form.
template<int KS, int JV, int JB, int WOFF>
__device__ __forceinline__ void conv_mfma_g(const ushort* X_th, const ushort* __restrict__ wg,
                                            ushort* tc_h, const float* bias0,
                                            int mp, int ntg, int quad, int c16) {
  f32x4 accA[3], accB[3];
  #pragma unroll
  for (int i = 0; i < 3; ++i) { accA[i] = (f32x4){0.f,0.f,0.f,0.f}; accB[i] = (f32x4){0.f,0.f,0.f,0.f}; }
  #pragma unroll
  for (int dt = 0; dt < KS; ++dt) {
    bf16x8 A0 = *(const bf16x8*)&wg[WOFF + (dt * 64 + mp * 16 + c16) * 32 + quad * 8];
    bf16x8 A1 = *(const bf16x8*)&wg[WOFF + (dt * 64 + (mp + 2) * 16 + c16) * 32 + quad * 8];
    #pragma unroll
    for (int i = 0; i < 3; ++i) {
      int nt = ntg * 3 + i;
      int j = nt >> 1, sh = nt & 1;
      bf16x8 Bf = *(const bf16x8*)&X_th[(sh * 16 + c16) * 584 + (j + dt) * 32 + quad * 8];
      accA[i] = __builtin_amdgcn_mfma_f32_16x16x32_bf16(A0, Bf, accA[i], 0, 0, 0);
      accB[i] = __builtin_amdgcn_mfma_f32_16x16x32_bf16(A1, Bf, accB[i], 0, 0, 0);
    }
  }
  int sxq = ((quad & 1) << 5) ^ ((quad & 2) << 1);   // r-independent part of the swizzle
  #pragma unroll
  for (int i = 0; i < 3; ++i) {
    int nt = ntg * 3 + i, j = nt >> 1, sh = nt & 1;
    if (j < JV) {
      int s = sh * 16 + c16;
      int sx = ((s & 15) << 1) ^ sxq;
      #pragma unroll
      for (int r = 0; r < 4; ++r) {
        int cc = mp * 16 + quad * 4 + r;
        float a = accA[i][r] + bias0[cc];
        float g = accB[i][r] + bias0[cc + 32];
        float e2a = __expf(2.f * a);
        float th = 1.f - 2.f / (e2a + 1.f);
        float sg = 1.f / (1.f + __expf(-g));
        tc_h[((s * 32 + cc) * 32 + (JB + j)) ^ sx] = f2bf(th * sg);
      }
    }
  }
}

__global__ __launch_bounds__(1024) void k8_fused(
                       const float* __restrict__ rhs, const float* __restrict__ Theta,
                       const float* __restrict__ x, const float* __restrict__ rw,
                       const float* __restrict__ rb,
                       const ushort* __restrict__ wg,
                       const float* __restrict__ b3, const float* __restrict__ b5,
                       const float* __restrict__ b7,
                       const float* __restrict__ fw, const float* __restrict__ fb,
                       const float* __restrict__ gf, const float* __restrict__ bf,
                       float* __restrict__ out) {
  int bn0 = blockIdx.x * 32;
  int b = bn0 >> 10, n0 = bn0 & 1023;

  __shared__ __align__(16) char uR[50176];
  ushort* X_th = (ushort*)uR;                 // [32 s][18 t][32 ic], site stride 584 shorts
  float*  v_l  = (float*)uR;                  // [32][391] overlay (X dead by then)
  __shared__ __align__(16) ushort tc_h[1024 * 32];
  __shared__ float rhs_l[32 * 36];
  __shared__ float Th_l[96];
  __shared__ float xr_l[32 * 12];
  __shared__ float fw_l[288];
  __shared__ float fb_l[12];
  __shared__ float bias_l[3][64];
  __shared__ float rw_l[32], rb_l[32], gf_l[32], bf_l[32];
  __shared__ float stm[384], str[384];

  int tid = threadIdx.x;
  int w = tid >> 6, lane = tid & 63, quad = lane >> 4, c16 = lane & 15;
  int mp = w & 1, ntg = w >> 1;
  int c = (tid >> 3) & 31;
  int site = (tid & 7) | ((tid >> 8) << 3);

  for (int idx = tid; idx < 1152; idx += 1024) {
    int s = idx / 36, r = idx - s * 36, k = r / 12, t = r - k * 12;
    rhs_l[idx] = rhs[((size_t)(b * 3 + k) * N_ + n0 + s) * 12 + t];
  }
  if (tid < 384) xr_l[tid] = x[(size_t)(b * N_ + n0) * 12 + tid];
  if (tid < 96) Th_l[tid] = Theta[tid];
  if (tid < 288) fw_l[tid] = fw[tid];
  if (tid < 12) fb_l[tid] = fb[tid];
  if (tid < 64) { bias_l[0][tid] = b3[tid]; bias_l[1][tid] = b5[tid]; bias_l[2][tid] = b7[tid]; }
  if (tid >= 64 && tid < 96)  rw_l[tid - 64] = rw[tid - 64];
  if (tid >= 96 && tid < 128) rb_l[tid - 96] = rb[tid - 96];
  if (tid >= 128 && tid < 160) gf_l[tid - 128] = gf[tid - 128];
  if (tid >= 160 && tid < 192) bf_l[tid - 160] = bf[tid - 160];
  __syncthreads();

  {
    float th0 = Th_l[c], th1 = Th_l[32 + c], th2 = Th_l[64 + c];
    const float* rs_ = &rhs_l[site * 36];
    ushort* xo = &X_th[site * 584 + c];
    #pragma unroll
    for (int t = 0; t < 12; ++t) {
      float a = rs_[t] * th0 + rs_[12 + t] * th1 + rs_[24 + t] * th2;
      xo[t * 32] = f2bf(fmaxf(a, 0.f));
    }
  }
  for (int idx = tid; idx < 32 * 6 * 32; idx += 1024) {
    int s = idx / 192, r2 = idx - s * 192, tt = r2 >> 5, ic = r2 & 31;
    X_th[s * 584 + (12 + tt) * 32 + ic] = 0;
  }
  __syncthreads();

  // convs back-to-back: weights from global, disjoint tc_h regions -> no barriers between
  conv_mfma_g<3, 10, 0,      0>(X_th, wg, tc_h, &bias_l[0][0], mp, ntg, quad, c16);
  conv_mfma_g<5, 8, 10,   6144>(X_th, wg, tc_h, &bias_l[1][0], mp, ntg, quad, c16);
  conv_mfma_g<7, 6, 18,  16384>(X_th, wg, tc_h, &bias_l[2][0], mp, ntg, quad, c16);
  __syncthreads();

  float tcv[24];
  {
    int rb2 = (site * 32 + c) * 32;
    int sxr = ((site & 15) << 1) ^ ((c & 4) << 3) ^ ((c & 8) >> 1);
    #pragma unroll
    for (int j = 0; j < 24; ++j)
      tcv[j] = __uint_as_float(((uint)tc_h[(rb2 + j) ^ sxr]) << 16);
  }
  float o[12];
  #pragma unroll
  for (int t = 0; t < 12; ++t) o[t] = fb_l[t];
  #pragma unroll
  for (int j = 0; j < 24; ++j) {
    const float4* fp = (const float4*)&fw_l[j * 12];
    float4 f0 = fp[0], f1 = fp[1], f2 = fp[2];
    float fr[12] = {f0.x, f0.y, f0.z, f0.w, f1.x, f1.y, f1.z, f1.w, f2.x, f2.y, f2.z, f2.w};
    #pragma unroll
    for (int t = 0; t < 12; ++t) o[t] = fmaf(tcv[j], fr[t], o[t]);
  }

  float v[12];
  {
    float rwc = rw_l[c], rbc = rb_l[c];
    const float* xs = &xr_l[site * 12];
    float* vo = &v_l[site * 391 + c * 12];
    #pragma unroll
    for (int t = 0; t < 12; ++t) {
      float xres = xs[t] * rwc + rbc;
      v[t] = fmaxf(xres + fmaxf(o[t], 0.f), 0.f);
      vo[t] = v[t];
    }
  }
  __syncthreads();
  if (tid < 384) {
    int s = tid / 12, t = tid - s * 12;
    float sm = 0.f, s2 = 0.f;
    #pragma unroll 8
    for (int cc = 0; cc < 32; ++cc) {
      float u = v_l[s * 391 + cc * 12 + t];
      sm += u; s2 += u * u;
    }
    float m = sm * (1.f / 32.f);
    stm[tid] = m;
    str[tid] = rsqrtf(s2 * (1.f / 32.f) - m * m + 1e-5f);
  }
  __syncthreads();
  {
    float gfc = gf_l[c], bfc = bf_l[c];
    const float* sm_ = &stm[site * 12];
    const float* sr_ = &str[site * 12];
    float q[12];
    #pragma unroll
    for (int t = 0; t < 12; ++t) q[t] = (v[t] - sm_[t]) * sr_[t] * gfc + bfc;
    float* op = &out[(size_t)(bn0 + site) * 384 + c * 12];
    ((float4*)op)[0] = make_float4(q[0], q[1], q[2], q[3]);
    ((float4*)op)[1] = make_float4(q[4], q[5], q[6], q[7]);
    ((float4*)op)[2] = make_float4(q[8], q[9], q[10], q[11]);
  }
}

// ---------------- launch ----------------
extern "C" void kernel_launch(void* const* d_in, const int* in_sizes, int n_in,
                              void* d_out, int out_size, void* d_ws, size_t ws_size,
                              hipStream_t stream) {
  const float* x       = (const float*)d_in[0];
  const float* res_att = (const float*)d_in[1];
  const float* posT    = (const float*)d_in[2];
  const float* gT      = (const float*)d_in[3];
  const float* bT      = (const float*)d_in[4];
  const float* WQt     = (const float*)d_in[5];
  const float* WKt     = (const float*)d_in[6];
  const float* WVt     = (const float*)d_in[7];
  const float* fct     = (const float*)d_in[8];
  const float* pcw     = (const float*)d_in[9];
  const float* pcb     = (const float*)d_in[10];
  const float* posS    = (const float*)d_in[11];
  const float* gS      = (const float*)d_in[12];
  const float* bS      = (const float*)d_in[13];
  const float* WQs     = (const float*)d_in[14];
  const float* WKs     = (const float*)d_in[15];
  const float* cheb    = (const float*)d_in[16];
  const float* adj     = (const float*)d_in[17];
  const float* mask    = (const float*)d_in[18];
  const float* Theta   = (const float*)d_in[19];
  const float* w3      = (const float*)d_in[20];
  const float* b3      = (const float*)d_in[21];
  const float* w5      = (const float*)d_in[22];
  const float* b5      = (const float*)d_in[23];
  const float* w7      = (const float*)d_in[24];
  const float* b7      = (const float*)d_in[25];
  const float* rw      = (const float*)d_in[26];
  const float* rb      = (const float*)d_in[27];
  const float* fw      = (const float*)d_in[28];
  const float* fb      = (const float*)d_in[29];
  const float* gf      = (const float*)d_in[30];
  const float* bf      = (const float*)d_in[31];

  float* ws = (float*)d_ws;
  float* TEmx = ws;                         // 196608
  float* qkv  = TEmx + 196608;              // 55296 (reused: wg = bf16 GTU weights)
  float* ctx  = qkv + 55296;                // 18432
  float* TAT  = ctx + 18432;                // 196608
  float* SEmx = TAT + 196608;               // 8388608 slot: part @0 (<=221184), pk @+1048576
  float* Qsf  = SEmx + 8388608;             // 1572864 slots (bf16 uses half)
  float* Ksf  = Qsf + 1572864;              // 1572864
  float* rhs  = Ksf + 1572864;              // 589824
  ushort* wpre = (ushort*)(rhs + 589824);   // 98304 shorts
  ushort* wg   = (ushort*)qkv;              // 30720 shorts, inside the unused qkv slot
  float* part = SEmx;                       // k2 partials (dead after k3a); disjoint from pk

  __hip_bfloat16* Qh = (__hip_bfloat16*)Qsf;
  __hip_bfloat16* Kh = (__hip_bfloat16*)Ksf;
  uint* pk = (uint*)(SEmx + 1048576);       // 3M uints = 12 MB, disjoint from part

  float* out  = (float*)d_out;
  float* reAt = out + 6291456;

  k_prepack<<<3576, 256, 0, stream>>>(adj, mask, cheb, pk, WQs, WKs, wpre,
                                      w3, w5, w7, wg);
  k1_temporal_ln<<<B_ * T_, 256, 0, stream>>>(x, posT, gT, bT, TEmx);
  k2_qkv<<<dim3(4, B_ * T_), 256, 0, stream>>>(TEmx, WQt, WKt, WVt, part);
  k3a_attn<<<B_ * H_, 256, 0, stream>>>(part, res_att, reAt, ctx);
  k3b_tat<<<B_ * T_, 1024, 0, stream>>>(ctx, fct, TEmx, TAT);
  k5_qks<<<dim3(N_ / 32, B_), 256, 0, stream>>>(TAT, pcw, pcb, posS, gS, bS, wpre, Qh, Kh);
  k6_spatial<<<B_ * K_ * (N_ / 32), 256, 0, stream>>>(Qh, Kh, pk, x, rhs);
  k8_fused<<<B_ * N_ / 32, 1024, 0, stream>>>(rhs, Theta, x, rw, rb,
                                              wg, b3, b5, b7, fw, fb, gf, bf, out);
}